// Round 1
// baseline (3076.354 us; speedup 1.0000x reference)
//
#include <hip/hip_runtime.h>
#include <math.h>

// NaryTreeLSTM on MI355X — round 1: correct fp32 baseline, GEMM-shaped.
// DEPTH=16, HID=INP=256, K=2, TOTAL=131071.
//
// Per internal level d (n = 2^d nodes):
//   Z   = [xs | Hs]                (n x 512), Hs = h_child[2j] + h_child[2j+1]
//   pre = Z @ Wbig^T + bbig        (n x 1280)
//   Wbig rows: [0:256)=[Wi|Ui], [256:512)=[Wo|Uo], [512:768)=[Wu|Uu],
//              [768:1024)=[Wf|Wfk0], [1024:1280)=[Wf|Wfk1]
//   i=sig, o=sig, u=tanh, f0=sig, f1=sig
//   c = i*u + f0*c_child[2j] + f1*c_child[2j+1];  h = o*tanh(c)
// Leaf level: pre = xs @ [Wi;Wo;Wu]^T + b (65536 x 768); c=i*u; h=o*tanh(c)

#define LEAF_N   65536
#define LEAF_ST  65535

__device__ __forceinline__ float sigf(float x) { return 1.0f / (1.0f + expf(-x)); }

// ---------------- weight packing ----------------
__global__ __launch_bounds__(256) void pack_weights(
    const float* __restrict__ Wi, const float* __restrict__ bi,
    const float* __restrict__ Wf, const float* __restrict__ bf,
    const float* __restrict__ Wo, const float* __restrict__ bo,
    const float* __restrict__ Wu, const float* __restrict__ bu,
    const float* __restrict__ Ui, const float* __restrict__ Uo,
    const float* __restrict__ Uu, const float* __restrict__ Wfk,
    float* __restrict__ Wbig, float* __restrict__ Wleaf,
    float* __restrict__ bbig, float* __restrict__ bleaf)
{
    int idx = blockIdx.x * 256 + threadIdx.x;
    const int NWB = 1280 * 512;
    const int NWL = 768 * 256;
    if (idx < NWB) {
        int r = idx >> 9, k = idx & 511;
        int g = r >> 8, rr = r & 255;
        float v;
        if (k < 256) {
            const float* W = (g == 0) ? Wi : (g == 1) ? Wo : (g == 2) ? Wu : Wf;
            v = W[rr * 256 + k];
        } else {
            int kk = k - 256;
            v = (g == 0) ? Ui[rr * 256 + kk]
              : (g == 1) ? Uo[rr * 256 + kk]
              : (g == 2) ? Uu[rr * 256 + kk]
              : (g == 3) ? Wfk[rr * 256 + kk]
                         : Wfk[65536 + rr * 256 + kk];
        }
        Wbig[idx] = v;
    } else if (idx < NWB + NWL) {
        int j = idx - NWB;
        int r = j >> 8, k = j & 255;
        int g = r >> 8, rr = r & 255;
        const float* W = (g == 0) ? Wi : (g == 1) ? Wo : Wu;
        Wleaf[j] = W[rr * 256 + k];
    } else if (idx < NWB + NWL + 1280) {
        int r = idx - NWB - NWL;
        int g = r >> 8, rr = r & 255;
        bbig[r] = (g == 0) ? bi[rr] : (g == 1) ? bo[rr] : (g == 2) ? bu[rr] : bf[rr];
    } else if (idx < NWB + NWL + 1280 + 768) {
        int r = idx - NWB - NWL - 1280;
        int g = r >> 8, rr = r & 255;
        bleaf[r] = (g == 0) ? bi[rr] : (g == 1) ? bo[rr] : bu[rr];
    }
}

// ---------------- Z prep: [xs | h2j + h2j+1] ----------------
__global__ __launch_bounds__(256) void prep_Z(
    const float* __restrict__ x, const float* __restrict__ hsrc,
    float* __restrict__ Z, int n, int start)
{
    int idx = blockIdx.x * 256 + threadIdx.x;
    if (idx >= n * 512) return;
    int j = idx >> 9, k = idx & 511;
    float v;
    if (k < 256) {
        v = x[(size_t)(start + j) * 256 + k];
    } else {
        int kk = k - 256;
        v = hsrc[(size_t)(2 * j) * 256 + kk] + hsrc[(size_t)(2 * j + 1) * 256 + kk];
    }
    Z[idx] = v;
}

// ---------------- fp32 NT-GEMM: C[m][n] = sum_k A[m][k]*B[n][k] + bias[n] ----------------
// 64x64 tile, Kc=16, 256 threads (16x16, each 4x4 micro-tile).
__global__ __launch_bounds__(256) void gemm_nt(
    const float* __restrict__ A, int lda, int M,
    const float* __restrict__ B, int ldb, int Kdim,
    const float* __restrict__ bias, float* __restrict__ C, int ldc)
{
    __shared__ float As[64][17];
    __shared__ float Bs[64][17];

    int tid = threadIdx.x;
    int bm = blockIdx.x * 64;
    int bn = blockIdx.y * 64;

    int lr = tid >> 2;         // 0..63 staging row
    int lk = (tid & 3) * 4;    // 0,4,8,12 staging col group

    int tm = (tid >> 4) * 4;   // 0..60
    int tn = (tid & 15) * 4;   // 0..60

    float acc[4][4];
#pragma unroll
    for (int i = 0; i < 4; i++)
#pragma unroll
        for (int j = 0; j < 4; j++) acc[i][j] = 0.0f;

    for (int k0 = 0; k0 < Kdim; k0 += 16) {
        float4 av = make_float4(0.f, 0.f, 0.f, 0.f);
        int ar = bm + lr;
        if (ar < M) av = *(const float4*)(A + (size_t)ar * lda + k0 + lk);
        float4 bv = *(const float4*)(B + (size_t)(bn + lr) * ldb + k0 + lk);

        As[lr][lk + 0] = av.x; As[lr][lk + 1] = av.y;
        As[lr][lk + 2] = av.z; As[lr][lk + 3] = av.w;
        Bs[lr][lk + 0] = bv.x; Bs[lr][lk + 1] = bv.y;
        Bs[lr][lk + 2] = bv.z; Bs[lr][lk + 3] = bv.w;
        __syncthreads();

#pragma unroll
        for (int k = 0; k < 16; k++) {
            float a0 = As[tm + 0][k], a1 = As[tm + 1][k];
            float a2 = As[tm + 2][k], a3 = As[tm + 3][k];
            float b0 = Bs[tn + 0][k], b1 = Bs[tn + 1][k];
            float b2 = Bs[tn + 2][k], b3 = Bs[tn + 3][k];
            acc[0][0] += a0 * b0; acc[0][1] += a0 * b1; acc[0][2] += a0 * b2; acc[0][3] += a0 * b3;
            acc[1][0] += a1 * b0; acc[1][1] += a1 * b1; acc[1][2] += a1 * b2; acc[1][3] += a1 * b3;
            acc[2][0] += a2 * b0; acc[2][1] += a2 * b1; acc[2][2] += a2 * b2; acc[2][3] += a2 * b3;
            acc[3][0] += a3 * b0; acc[3][1] += a3 * b1; acc[3][2] += a3 * b2; acc[3][3] += a3 * b3;
        }
        __syncthreads();
    }

#pragma unroll
    for (int i = 0; i < 4; i++) {
        int r = bm + tm + i;
        if (r >= M) continue;
#pragma unroll
        for (int j = 0; j < 4; j++) {
            int cN = bn + tn + j;
            C[(size_t)r * ldc + cN] = acc[i][j] + bias[cN];
        }
    }
}

// ---------------- epilogues ----------------
__global__ __launch_bounds__(256) void leaf_epi(
    const float* __restrict__ pre, float* __restrict__ h, float* __restrict__ c)
{
    int idx = blockIdx.x * 256 + threadIdx.x;
    int j = idx >> 8, r = idx & 255;
    const float* p = pre + (size_t)j * 768;
    float iv = sigf(p[r]);
    float ov = sigf(p[256 + r]);
    float uv = tanhf(p[512 + r]);
    float cv = iv * uv;
    c[idx] = cv;
    h[idx] = ov * tanhf(cv);
}

__global__ __launch_bounds__(256) void int_epi(
    const float* __restrict__ pre, const float* __restrict__ csrc,
    float* __restrict__ h, float* __restrict__ c)
{
    int idx = blockIdx.x * 256 + threadIdx.x;
    int j = idx >> 8, r = idx & 255;
    const float* p = pre + (size_t)j * 1280;
    float iv = sigf(p[r]);
    float ov = sigf(p[256 + r]);
    float uv = tanhf(p[512 + r]);
    float f0 = sigf(p[768 + r]);
    float f1 = sigf(p[1024 + r]);
    float cv = iv * uv
             + f0 * csrc[(size_t)(2 * j) * 256 + r]
             + f1 * csrc[(size_t)(2 * j + 1) * 256 + r];
    c[idx] = cv;
    h[idx] = ov * tanhf(cv);
}

__global__ __launch_bounds__(512) void copy_out(
    const float* __restrict__ h, const float* __restrict__ c, float* __restrict__ out)
{
    int t = threadIdx.x;
    out[t] = (t < 256) ? h[t] : c[t - 256];
}

// ---------------- launch ----------------
extern "C" void kernel_launch(void* const* d_in, const int* in_sizes, int n_in,
                              void* d_out, int out_size, void* d_ws, size_t ws_size,
                              hipStream_t stream)
{
    const float* x   = (const float*)d_in[0];
    const float* Wi  = (const float*)d_in[1];
    const float* bi  = (const float*)d_in[2];
    const float* Wf  = (const float*)d_in[3];
    const float* bf  = (const float*)d_in[4];
    const float* Wo  = (const float*)d_in[5];
    const float* bo  = (const float*)d_in[6];
    const float* Wu  = (const float*)d_in[7];
    const float* bu  = (const float*)d_in[8];
    const float* Ui  = (const float*)d_in[9];
    const float* Uo  = (const float*)d_in[10];
    const float* Uu  = (const float*)d_in[11];
    const float* Wfk = (const float*)d_in[12];
    float* out = (float*)d_out;
    float* ws  = (float*)d_ws;

    // workspace carve-up (floats)
    size_t off = 0;
    float* Wbig  = ws + off; off += (size_t)1280 * 512;   // 655360
    float* Wleaf = ws + off; off += (size_t)768 * 256;    // 196608
    float* bbig  = ws + off; off += 1280;
    float* bleaf = ws + off; off += 768;
    float* Z     = ws + off; off += (size_t)32768 * 512;  // 64 MB
    float* pre   = ws + off; off += (size_t)65536 * 768;  // 201 MB (also >= 32768*1280)
    float* hA    = ws + off; off += (size_t)65536 * 256;  // 64 MB
    float* cA    = ws + off; off += (size_t)65536 * 256;  // 64 MB
    float* hB    = ws + off; off += (size_t)32768 * 256;  // 32 MB
    float* cB    = ws + off; off += (size_t)32768 * 256;  // 32 MB
    (void)ws_size; (void)in_sizes; (void)n_in; (void)out_size;

    // 1) pack weights (854016 elements)
    pack_weights<<<3336, 256, 0, stream>>>(Wi, bi, Wf, bf, Wo, bo, Wu, bu,
                                           Ui, Uo, Uu, Wfk, Wbig, Wleaf, bbig, bleaf);

    // 2) leaf level: pre = x[leaf] @ Wleaf^T + bleaf ; epilogue -> hA,cA
    gemm_nt<<<dim3(LEAF_N / 64, 768 / 64), 256, 0, stream>>>(
        x + (size_t)LEAF_ST * 256, 256, LEAF_N, Wleaf, 256, 256, bleaf, pre, 768);
    leaf_epi<<<LEAF_N, 256, 0, stream>>>(pre, hA, cA);

    // 3) internal levels d = 15 .. 0 (src = A when d odd)
    for (int d = 15; d >= 0; d--) {
        int n = 1 << d;
        int start = (1 << d) - 1;
        float* hsrc = (d & 1) ? hA : hB;
        float* csrc = (d & 1) ? cA : cB;
        float* hdst = (d & 1) ? hB : hA;
        float* cdst = (d & 1) ? cB : cA;

        prep_Z<<<n * 2, 256, 0, stream>>>(x, hsrc, Z, n, start);
        gemm_nt<<<dim3((n + 63) / 64, 1280 / 64), 256, 0, stream>>>(
            Z, 512, n, Wbig, 512, 512, bbig, pre, 1280);
        int_epi<<<n, 256, 0, stream>>>(pre, csrc, hdst, cdst);
    }

    // 4) output: [h(1x256), c(1x256)] — final dst is A (d=0 writes A)
    copy_out<<<1, 512, 0, stream>>>(hA, cA, out);
}

// Round 2
// 994.261 us; speedup vs baseline: 3.0941x; 3.0941x over previous
//
#include <hip/hip_runtime.h>
#include <math.h>

// NaryTreeLSTM on MI355X — round 2: bf16 MFMA GEMM (fp32 accumulate).
// DEPTH=16, HID=INP=256, K=2, TOTAL=131071.
//
// Per internal level d (n = 2^d nodes):
//   Z   = [xs | Hs]  (n x 512, bf16), Hs = h_child[2j] + h_child[2j+1]
//   pre = Z @ Wbig^T + bbig  (n x 1280, fp32)
//   Wbig rows: [0:256)=[Wi|Ui], [256:512)=[Wo|Uo], [512:768)=[Wu|Uu],
//              [768:1024)=[Wf|Wfk0], [1024:1280)=[Wf|Wfk1]
//   c = sig(i)*tanh(u) + sig(f0)*c0 + sig(f1)*c1;  h = sig(o)*tanh(c)
// Leaf level: pre = xs_bf16 @ [Wi;Wo;Wu]^T + b (65536 x 768)

#define LEAF_N   65536
#define LEAF_ST  65535

typedef __attribute__((ext_vector_type(8))) short bf16x8;
typedef __attribute__((ext_vector_type(4))) float f32x4;

__device__ __forceinline__ float sigf(float x) { return 1.0f / (1.0f + expf(-x)); }

__device__ __forceinline__ unsigned short f2bf(float f) {
    union { float f; unsigned u; } v; v.f = f;
    unsigned r = v.u + 0x7fffu + ((v.u >> 16) & 1u);   // RNE
    return (unsigned short)(r >> 16);
}

// ---------------- weight packing (fp32 -> bf16) ----------------
__global__ __launch_bounds__(256) void pack_weights(
    const float* __restrict__ Wi, const float* __restrict__ bi,
    const float* __restrict__ Wf, const float* __restrict__ bf,
    const float* __restrict__ Wo, const float* __restrict__ bo,
    const float* __restrict__ Wu, const float* __restrict__ bu,
    const float* __restrict__ Ui, const float* __restrict__ Uo,
    const float* __restrict__ Uu, const float* __restrict__ Wfk,
    unsigned short* __restrict__ Wbig, unsigned short* __restrict__ Wleaf,
    float* __restrict__ bbig, float* __restrict__ bleaf)
{
    int idx = blockIdx.x * 256 + threadIdx.x;
    const int NWB = 1280 * 512;
    const int NWL = 768 * 256;
    if (idx < NWB) {
        int r = idx >> 9, k = idx & 511;
        int g = r >> 8, rr = r & 255;
        float v;
        if (k < 256) {
            const float* W = (g == 0) ? Wi : (g == 1) ? Wo : (g == 2) ? Wu : Wf;
            v = W[rr * 256 + k];
        } else {
            int kk = k - 256;
            v = (g == 0) ? Ui[rr * 256 + kk]
              : (g == 1) ? Uo[rr * 256 + kk]
              : (g == 2) ? Uu[rr * 256 + kk]
              : (g == 3) ? Wfk[rr * 256 + kk]
                         : Wfk[65536 + rr * 256 + kk];
        }
        Wbig[idx] = f2bf(v);
    } else if (idx < NWB + NWL) {
        int j = idx - NWB;
        int r = j >> 8, k = j & 255;
        int g = r >> 8, rr = r & 255;
        const float* W = (g == 0) ? Wi : (g == 1) ? Wo : Wu;
        Wleaf[j] = f2bf(W[rr * 256 + k]);
    } else if (idx < NWB + NWL + 1280) {
        int r = idx - NWB - NWL;
        int g = r >> 8, rr = r & 255;
        bbig[r] = (g == 0) ? bi[rr] : (g == 1) ? bo[rr] : (g == 2) ? bu[rr] : bf[rr];
    } else if (idx < NWB + NWL + 1280 + 768) {
        int r = idx - NWB - NWL - 1280;
        int g = r >> 8, rr = r & 255;
        bleaf[r] = (g == 0) ? bi[rr] : (g == 1) ? bo[rr] : bu[rr];
    }
}

// ---------------- leaf x slab fp32 -> bf16 (8 elems/thread) ----------------
__global__ __launch_bounds__(256) void cvt_leaf(
    const float* __restrict__ x, unsigned short* __restrict__ Xbf)
{
    int t = blockIdx.x * 256 + threadIdx.x;          // 2,097,152 threads
    const float* s = x + (size_t)t * 8;
    unsigned short r[8];
#pragma unroll
    for (int i = 0; i < 8; i++) r[i] = f2bf(s[i]);
    *(uint4*)(Xbf + (size_t)t * 8) = *(uint4*)r;
}

// ---------------- Z prep: [xs | h2j + h2j+1] -> bf16 (8 elems/thread) -------
__global__ __launch_bounds__(256) void prep_Z(
    const float* __restrict__ x, const float* __restrict__ hsrc,
    unsigned short* __restrict__ Z, int n, int start)
{
    int t = blockIdx.x * 256 + threadIdx.x;
    int e = t * 8;
    if (e >= n * 512) return;
    int j = e >> 9, k = e & 511;
    unsigned short r[8];
    if (k < 256) {
        const float* s = x + (size_t)(start + j) * 256 + k;
#pragma unroll
        for (int i = 0; i < 8; i++) r[i] = f2bf(s[i]);
    } else {
        int kk = k - 256;
        const float* h0 = hsrc + (size_t)(2 * j) * 256 + kk;
        const float* h1 = hsrc + (size_t)(2 * j + 1) * 256 + kk;
#pragma unroll
        for (int i = 0; i < 8; i++) r[i] = f2bf(h0[i] + h1[i]);
    }
    *(uint4*)(Z + (size_t)e) = *(uint4*)r;
}

// ---------------- bf16 MFMA NT-GEMM ----------------
// C[m][n] = sum_k A[m][k]*B[n][k] + bias[n], fp32 out.
// 128x128 tile, BK=64, 256 threads = 4 waves (2x2 of 64x64), 4x4 frags of
// 16x16x32 MFMA. LDS rows padded 64->72 bf16 (144 B) => 2-way bank alias (free).
__global__ __launch_bounds__(256) void gemm_bf16(
    const unsigned short* __restrict__ A, int lda, int M,
    const unsigned short* __restrict__ B, int ldb, int Kdim,
    const float* __restrict__ bias, float* __restrict__ C, int ldc)
{
    constexpr int LP = 72;
    __shared__ unsigned short As[128 * LP];
    __shared__ unsigned short Bs[128 * LP];

    const int tid  = threadIdx.x;
    const int wave = tid >> 6;
    const int lane = tid & 63;
    const int bm = blockIdx.x * 128;
    const int bn = blockIdx.y * 128;

    const int srow = tid >> 3;          // 0..31 (+32*pass)
    const int scol = (tid & 7) * 8;     // 0,8,..,56

    const int wm = (wave >> 1) * 64;
    const int wn = (wave & 1) * 64;
    const int lm = lane & 15;           // frag row (A) / frag col-row (B)
    const int kq = (lane >> 4) * 8;     // k offset within frag

    f32x4 acc[4][4] = {};

    for (int k0 = 0; k0 < Kdim; k0 += 64) {
#pragma unroll
        for (int p = 0; p < 4; p++) {
            int r = srow + p * 32;
            int gr = bm + r;
            uint4 av = make_uint4(0u, 0u, 0u, 0u);
            if (gr < M) av = *(const uint4*)(A + (size_t)gr * lda + k0 + scol);
            *(uint4*)(As + r * LP + scol) = av;
            uint4 bv = *(const uint4*)(B + (size_t)(bn + r) * ldb + k0 + scol);
            *(uint4*)(Bs + r * LP + scol) = bv;
        }
        __syncthreads();

#pragma unroll
        for (int kk = 0; kk < 64; kk += 32) {
            bf16x8 af[4], bfr[4];
#pragma unroll
            for (int i = 0; i < 4; i++)
                af[i] = *(const bf16x8*)(As + (wm + i * 16 + lm) * LP + kk + kq);
#pragma unroll
            for (int j = 0; j < 4; j++)
                bfr[j] = *(const bf16x8*)(Bs + (wn + j * 16 + lm) * LP + kk + kq);
#pragma unroll
            for (int i = 0; i < 4; i++)
#pragma unroll
                for (int j = 0; j < 4; j++)
                    acc[i][j] = __builtin_amdgcn_mfma_f32_16x16x32_bf16(
                        af[i], bfr[j], acc[i][j], 0, 0, 0);
        }
        __syncthreads();
    }

    // C/D layout: col = lane&15, row = (lane>>4)*4 + reg
    const int cr0 = (lane >> 4) * 4;
    const int cc  = lane & 15;
#pragma unroll
    for (int i = 0; i < 4; i++) {
#pragma unroll
        for (int reg = 0; reg < 4; reg++) {
            int r = bm + wm + i * 16 + cr0 + reg;
            if (r >= M) continue;
#pragma unroll
            for (int j = 0; j < 4; j++) {
                int cn = bn + wn + j * 16 + cc;
                C[(size_t)r * ldc + cn] = acc[i][j][reg] + bias[cn];
            }
        }
    }
}

// ---------------- epilogues ----------------
__global__ __launch_bounds__(256) void leaf_epi(
    const float* __restrict__ pre, float* __restrict__ h, float* __restrict__ c)
{
    int idx = blockIdx.x * 256 + threadIdx.x;
    int j = idx >> 8, r = idx & 255;
    const float* p = pre + (size_t)j * 768;
    float iv = sigf(p[r]);
    float ov = sigf(p[256 + r]);
    float uv = tanhf(p[512 + r]);
    float cv = iv * uv;
    c[idx] = cv;
    h[idx] = ov * tanhf(cv);
}

__global__ __launch_bounds__(256) void int_epi(
    const float* __restrict__ pre, const float* __restrict__ csrc,
    float* __restrict__ h, float* __restrict__ c)
{
    int idx = blockIdx.x * 256 + threadIdx.x;
    int j = idx >> 8, r = idx & 255;
    const float* p = pre + (size_t)j * 1280;
    float iv = sigf(p[r]);
    float ov = sigf(p[256 + r]);
    float uv = tanhf(p[512 + r]);
    float f0 = sigf(p[768 + r]);
    float f1 = sigf(p[1024 + r]);
    float cv = iv * uv
             + f0 * csrc[(size_t)(2 * j) * 256 + r]
             + f1 * csrc[(size_t)(2 * j + 1) * 256 + r];
    c[idx] = cv;
    h[idx] = ov * tanhf(cv);
}

__global__ __launch_bounds__(512) void copy_out(
    const float* __restrict__ h, const float* __restrict__ c, float* __restrict__ out)
{
    int t = threadIdx.x;
    out[t] = (t < 256) ? h[t] : c[t - 256];
}

// ---------------- launch ----------------
extern "C" void kernel_launch(void* const* d_in, const int* in_sizes, int n_in,
                              void* d_out, int out_size, void* d_ws, size_t ws_size,
                              hipStream_t stream)
{
    const float* x   = (const float*)d_in[0];
    const float* Wi  = (const float*)d_in[1];
    const float* bi  = (const float*)d_in[2];
    const float* Wf  = (const float*)d_in[3];
    const float* bf  = (const float*)d_in[4];
    const float* Wo  = (const float*)d_in[5];
    const float* bo  = (const float*)d_in[6];
    const float* Wu  = (const float*)d_in[7];
    const float* bu  = (const float*)d_in[8];
    const float* Ui  = (const float*)d_in[9];
    const float* Uo  = (const float*)d_in[10];
    const float* Uu  = (const float*)d_in[11];
    const float* Wfk = (const float*)d_in[12];
    float* out = (float*)d_out;
    char* ws   = (char*)d_ws;
    (void)ws_size; (void)in_sizes; (void)n_in; (void)out_size;

    // workspace carve-up (bytes, all regions 256B-aligned by construction)
    size_t off = 0;
    unsigned short* Wbig  = (unsigned short*)(ws + off); off += (size_t)1280 * 512 * 2;   // 1.25 MB
    unsigned short* Wleaf = (unsigned short*)(ws + off); off += (size_t)768 * 256 * 2;    // 384 KB
    float* bbig  = (float*)(ws + off); off += 1280 * 4;
    float* bleaf = (float*)(ws + off); off += 768 * 4 + 192;                               // pad to 256B
    unsigned short* Xbf = (unsigned short*)(ws + off); off += (size_t)65536 * 256 * 2;    // 32 MB
    unsigned short* Z   = (unsigned short*)(ws + off); off += (size_t)32768 * 512 * 2;    // 32 MB
    float* pre = (float*)(ws + off); off += (size_t)65536 * 768 * 4;                      // 192 MB
    float* hA  = (float*)(ws + off); off += (size_t)65536 * 256 * 4;                      // 64 MB
    float* cA  = (float*)(ws + off); off += (size_t)65536 * 256 * 4;                      // 64 MB
    float* hB  = (float*)(ws + off); off += (size_t)32768 * 256 * 4;                      // 32 MB
    float* cB  = (float*)(ws + off); off += (size_t)32768 * 256 * 4;                      // 32 MB

    // 1) pack weights -> bf16 (+ fp32 biases); convert leaf x slab -> bf16
    pack_weights<<<3336, 256, 0, stream>>>(Wi, bi, Wf, bf, Wo, bo, Wu, bu,
                                           Ui, Uo, Uu, Wfk, Wbig, Wleaf, bbig, bleaf);
    cvt_leaf<<<8192, 256, 0, stream>>>(x + (size_t)LEAF_ST * 256, Xbf);

    // 2) leaf level: pre = Xbf @ Wleaf^T + bleaf ; epilogue -> hA,cA
    gemm_bf16<<<dim3(LEAF_N / 128, 768 / 128), 256, 0, stream>>>(
        Xbf, 256, LEAF_N, Wleaf, 256, 256, bleaf, pre, 768);
    leaf_epi<<<LEAF_N, 256, 0, stream>>>(pre, hA, cA);

    // 3) internal levels d = 15 .. 0 (src = A when d odd)
    for (int d = 15; d >= 0; d--) {
        int n = 1 << d;
        int start = (1 << d) - 1;
        float* hsrc = (d & 1) ? hA : hB;
        float* csrc = (d & 1) ? cA : cB;
        float* hdst = (d & 1) ? hB : hA;
        float* cdst = (d & 1) ? cB : cA;

        prep_Z<<<(n * 64 + 255) / 256, 256, 0, stream>>>(x, hsrc, Z, n, start);
        gemm_bf16<<<dim3((n + 127) / 128, 1280 / 128), 256, 0, stream>>>(
            Z, 512, n, Wbig, 512, 512, bbig, pre, 1280);
        int_epi<<<n, 256, 0, stream>>>(pre, csrc, hdst, cdst);
    }

    // 4) output: [h(1x256), c(1x256)] — final dst is A (d=0 writes A)
    copy_out<<<1, 512, 0, stream>>>(hA, cA, out);
}